// Round 9
// baseline (163.996 us; speedup 1.0000x reference)
//
#include <hip/hip_runtime.h>

#define B_ 128
#define E_ 16
#define S_ 32768

constexpr int BLK  = 256;               // threads per block
constexpr int CH   = 2048;              // positions per chunk (2 float4/thread)
constexpr int NCH  = S_ / (2 * CH);     // 8 blocks per row (fwd+mirror chunks)

// Unconditional clamped vector load + data-flow masking (R6). Straddle fixed
// by a rare scalar branch.
#define GATHER(A, P)                                                          \
    {                                                                         \
        const int s_  = (P) - off;                                            \
        const int sc_ = s_ < 0 ? 0 : s_;        /* clamped: always in-bounds */\
        float4 v_ = *reinterpret_cast<const float4*>(rowbase + sc_);          \
        const float mk_ = s_ >= 0 ? 1.0f : 0.0f;                              \
        A.x = fmaf(v_.x, mk_, A.x);                                           \
        A.y = fmaf(v_.y, mk_, A.y);                                           \
        A.z = fmaf(v_.z, mk_, A.z);                                           \
        A.w = fmaf(v_.w, mk_, A.w);                                           \
        if (s_ > -4 && s_ < 0) {                /* straddle: 1 lane per (b,e) */\
            A.w += rowbase[(P) + 3 - off];      /* s_>=-3 => +3 valid */      \
            if (s_ >= -2) A.z += rowbase[(P) + 2 - off];                      \
            if (s_ >= -1) A.y += rowbase[(P) + 1 - off];                      \
        }                                                                     \
    }

__global__ __launch_bounds__(BLK, 8) void fused_scatter_norm(
    const float* __restrict__ events, const int* __restrict__ indices,
    float* __restrict__ out, float* __restrict__ pmax, unsigned* __restrict__ cnt)
{
    const int b  = blockIdx.y;
    const int cx = blockIdx.x;
    const int t  = (int)threadIdx.x;

    // Reflection pairing: forward chunk [cx*2048, +2048) and mirror chunk
    // [S - 2048*(cx+1), +2048) -> expected gather volume ~constant in cx.
    const int pF = cx * CH + 4 * t;                  // fwd:  a0 @ pF, a1 @ pF+1024
    const int pM = (S_ - CH * (cx + 1)) + 4 * t;     // mir:  a2 @ pM, a3 @ pM+1024

    float4 a0 = {0.f, 0.f, 0.f, 0.f};
    float4 a1 = {0.f, 0.f, 0.f, 0.f};
    float4 a2 = {0.f, 0.f, 0.f, 0.f};
    float4 a3 = {0.f, 0.f, 0.f, 0.f};

    const float* evb  = events + (size_t)b * (E_ * S_);
    const int*   idxb = indices + b * E_;

#pragma unroll 4
    for (int e = 0; e < E_; ++e) {
        const int off = idxb[e];                  // block-uniform scalar load
        const float* rowbase = evb + e * S_;      // events[b,e,0]
        GATHER(a0, pF)
        GATHER(a1, pF + 1024)
        GATHER(a2, pM)
        GATHER(a3, pM + 1024)
    }

    // ---- block max of the 16 per-thread sums ----
    float m = fmaxf(
        fmaxf(fmaxf(fmaxf(a0.x, a0.y), fmaxf(a0.z, a0.w)),
              fmaxf(fmaxf(a1.x, a1.y), fmaxf(a1.z, a1.w))),
        fmaxf(fmaxf(fmaxf(a2.x, a2.y), fmaxf(a2.z, a2.w)),
              fmaxf(fmaxf(a3.x, a3.y), fmaxf(a3.z, a3.w))));
#pragma unroll
    for (int d = 1; d < 64; d <<= 1)
        m = fmaxf(m, __shfl_xor(m, d, 64));

    __shared__ float wmax[BLK / 64];
    __shared__ float s_inv;
    if ((t & 63) == 0) wmax[t >> 6] = m;
    __syncthreads();

    if (t == 0) {
        float mm = fmaxf(fmaxf(wmax[0], wmax[1]), fmaxf(wmax[2], wmax[3]));
        // publish partial max, arrive at per-row barrier (normal launch; 1024
        // blocks at <=64 VGPR are always fully resident -> spin is safe)
        __hip_atomic_store(&pmax[b * NCH + cx], mm,
                           __ATOMIC_RELEASE, __HIP_MEMORY_SCOPE_AGENT);
        __hip_atomic_fetch_add(&cnt[b], 1u,
                               __ATOMIC_ACQ_REL, __HIP_MEMORY_SCOPE_AGENT);
        while (__hip_atomic_load(&cnt[b], __ATOMIC_ACQUIRE,
                                 __HIP_MEMORY_SCOPE_AGENT) < (unsigned)NCH)
            __builtin_amdgcn_s_sleep(8);
        float mr = -3.402823466e+38f;
#pragma unroll
        for (int c = 0; c < NCH; ++c)
            mr = fmaxf(mr, __hip_atomic_load(&pmax[b * NCH + c],
                                             __ATOMIC_RELAXED,
                                             __HIP_MEMORY_SCOPE_AGENT));
        s_inv = 1.0f / (mr + 1e-8f);
    }
    __syncthreads();
    const float inv = s_inv;

    // ---- normalize in-register, single output write ----
    float* ob = out + (size_t)b * S_;
    a0.x *= inv; a0.y *= inv; a0.z *= inv; a0.w *= inv;
    a1.x *= inv; a1.y *= inv; a1.z *= inv; a1.w *= inv;
    a2.x *= inv; a2.y *= inv; a2.z *= inv; a2.w *= inv;
    a3.x *= inv; a3.y *= inv; a3.z *= inv; a3.w *= inv;
    *reinterpret_cast<float4*>(ob + pF)        = a0;
    *reinterpret_cast<float4*>(ob + pF + 1024) = a1;
    *reinterpret_cast<float4*>(ob + pM)        = a2;
    *reinterpret_cast<float4*>(ob + pM + 1024) = a3;
}

extern "C" void kernel_launch(void* const* d_in, const int* in_sizes, int n_in,
                              void* d_out, int out_size, void* d_ws, size_t ws_size,
                              hipStream_t stream) {
    const float* events  = (const float*)d_in[0];
    const int*   indices = (const int*)d_in[1];
    float* out  = (float*)d_out;
    float*    pmax = (float*)d_ws;                    // B_*NCH floats = 4 KB
    unsigned* cnt  = (unsigned*)((char*)d_ws + B_ * NCH * sizeof(float));

    // barrier counters must be zero at every call (ws not re-poisoned)
    hipMemsetAsync(cnt, 0, B_ * sizeof(unsigned), stream);

    dim3 grid(NCH, B_);                 // 8 x 128 = 1024 blocks, normal launch
    fused_scatter_norm<<<grid, BLK, 0, stream>>>(events, indices, out, pmax, cnt);
}

// Round 11
// 47.878 us; speedup vs baseline: 3.4253x; 3.4253x over previous
//
#include <hip/hip_runtime.h>

#define B_ 128
#define E_ 16
#define S_ 32768

constexpr int BLK = 256;                // threads per block (kernel A)
constexpr int NCH = 16;                 // blocks per row
// Stripe-interleaved ownership: block cx owns 16 stripes of 128 positions,
// one per 2048-segment: p = s*2048 + cx*128 + (lane)*4, s = 0..15.
// Realized (not just expected) work is equal across blocks to within ~6%
// for ANY index draw -> no CU-level makespan imbalance.

typedef float f4v __attribute__((ext_vector_type(4)));   // builtin-compatible

// Unconditional clamped vector load + data-flow masking (R6). Streaming
// nontemporal load: events bytes are touched exactly once (keep L3 for 'out').
#define GATHER(A, P)                                                          \
    {                                                                         \
        const int s_  = (P) - off;                                            \
        const int sc_ = s_ < 0 ? 0 : s_;        /* clamped: always in-bounds */\
        f4v v_ = __builtin_nontemporal_load(                                  \
            reinterpret_cast<const f4v*>(rowbase + sc_));                     \
        const float mk_ = s_ >= 0 ? 1.0f : 0.0f;                              \
        A.x = fmaf(v_.x, mk_, A.x);                                           \
        A.y = fmaf(v_.y, mk_, A.y);                                           \
        A.z = fmaf(v_.z, mk_, A.z);                                           \
        A.w = fmaf(v_.w, mk_, A.w);                                           \
        if (s_ > -4 && s_ < 0) {                /* straddle: 1 lane per (b,e) */\
            A.w += rowbase[(P) + 3 - off];      /* s_>=-3 => +3 valid */      \
            if (s_ >= -2) A.z += rowbase[(P) + 2 - off];                      \
            if (s_ >= -1) A.y += rowbase[(P) + 1 - off];                      \
        }                                                                     \
    }

__global__ __launch_bounds__(BLK) void gather_sum_max(
    const float* __restrict__ events, const int* __restrict__ indices,
    float* __restrict__ out, float* __restrict__ pmax)
{
    const int b  = blockIdx.y;
    const int cx = blockIdx.x;
    const int t  = (int)threadIdx.x;

    // thread t, vector v in {0,1}: j = v*256 + t; stripe s = j>>5 (0..15);
    // p = s*2048 + cx*128 + (j&31)*4.  pB = pA + 8*2048.
    const int pA = ((t >> 5) << 11) + (cx << 7) + ((t & 31) << 2);
    const int pB = pA + 16384;

    float4 accA = {0.f, 0.f, 0.f, 0.f};
    float4 accB = {0.f, 0.f, 0.f, 0.f};

    const float* evb  = events + (size_t)b * (E_ * S_);
    const int*   idxb = indices + b * E_;

#pragma unroll 4
    for (int e = 0; e < E_; ++e) {
        const int off = idxb[e];                  // block-uniform scalar load
        const float* rowbase = evb + e * S_;      // events[b,e,0]
        GATHER(accA, pA)
        GATHER(accB, pB)
    }

    // aligned float4 stores of the raw sums (same stripe pattern)
    float* ob = out + (size_t)b * S_;
    *reinterpret_cast<float4*>(ob + pA) = accA;
    *reinterpret_cast<float4*>(ob + pB) = accB;

    // thread-local max of the 8 values
    float m = fmaxf(fmaxf(fmaxf(accA.x, accA.y), fmaxf(accA.z, accA.w)),
                    fmaxf(fmaxf(accB.x, accB.y), fmaxf(accB.z, accB.w)));

    // 64-lane butterfly reduce
#pragma unroll
    for (int d = 1; d < 64; d <<= 1)
        m = fmaxf(m, __shfl_xor(m, d, 64));

    __shared__ float wmax[BLK / 64];
    if ((t & 63) == 0) wmax[t >> 6] = m;
    __syncthreads();
    if (t == 0) {
        float mm = fmaxf(fmaxf(wmax[0], wmax[1]), fmaxf(wmax[2], wmax[3]));
        pmax[b * NCH + cx] = mm;   // unique slot: no memset, no atomics
    }
}

__global__ __launch_bounds__(256) void normalize_k(
    float* __restrict__ out, const float* __restrict__ pmax)
{
    const int b = blockIdx.y;
    // redundant per-block reduce of the 16 partial maxes (L2/L3-hot)
    const float* pm = pmax + b * NCH;
    float m = pm[0];
#pragma unroll
    for (int c = 1; c < NCH; ++c) m = fmaxf(m, pm[c]);
    const float inv = 1.0f / (m + 1e-8f);

    const int i = blockIdx.x * blockDim.x + threadIdx.x;   // float4 idx in row
    float4* o4 = reinterpret_cast<float4*>(out + (size_t)b * S_);
    float4 v = o4[i];
    v.x *= inv; v.y *= inv; v.z *= inv; v.w *= inv;
    o4[i] = v;
}

extern "C" void kernel_launch(void* const* d_in, const int* in_sizes, int n_in,
                              void* d_out, int out_size, void* d_ws, size_t ws_size,
                              hipStream_t stream) {
    const float* events  = (const float*)d_in[0];
    const int*   indices = (const int*)d_in[1];
    float* out  = (float*)d_out;
    float* pmax = (float*)d_ws;          // B_*NCH floats = 8 KB, fully rewritten
                                         // by kernel A every call

    dim3 gridA(NCH, B_);                 // 16 x 128 = 2048 blocks
    gather_sum_max<<<gridA, BLK, 0, stream>>>(events, indices, out, pmax);

    dim3 gridB(S_ / 4 / 256, B_);        // 32 x 128 = 4096 blocks
    normalize_k<<<gridB, 256, 0, stream>>>(out, pmax);
}

// Round 12
// 37.143 us; speedup vs baseline: 4.4153x; 1.2890x over previous
//
#include <hip/hip_runtime.h>

#define B_ 128
#define E_ 16
#define S_ 32768

constexpr int BLK = 256;                // threads per block (kernel A)
constexpr int NCH = 16;                 // blocks per row
// Stripe-256 interleaved ownership: row = 128 stripes of 256 positions.
// Block cx owns stripes {g*16 + cx : g = 0..7} -> spread every 4096 positions.
// Each 64-lane wave reads ONE contiguous 1KB line per event (same coalescing
// as R7's reflection pairing), but realized per-block work spread drops to
// ~3% RMS for any index draw (vs ~15% for reflection pairing).

// Unconditional clamped vector load + data-flow masking (R6, plain cached
// loads — R11 showed nontemporal regresses). Straddle fixed by rare branch.
#define GATHER(A, P)                                                          \
    {                                                                         \
        const int s_  = (P) - off;                                            \
        const int sc_ = s_ < 0 ? 0 : s_;        /* clamped: always in-bounds */\
        float4 v_ = *reinterpret_cast<const float4*>(rowbase + sc_);          \
        const float mk_ = s_ >= 0 ? 1.0f : 0.0f;                              \
        A.x = fmaf(v_.x, mk_, A.x);                                           \
        A.y = fmaf(v_.y, mk_, A.y);                                           \
        A.z = fmaf(v_.z, mk_, A.z);                                           \
        A.w = fmaf(v_.w, mk_, A.w);                                           \
        if (s_ > -4 && s_ < 0) {                /* straddle: 1 lane per (b,e) */\
            A.w += rowbase[(P) + 3 - off];      /* s_>=-3 => +3 valid */      \
            if (s_ >= -2) A.z += rowbase[(P) + 2 - off];                      \
            if (s_ >= -1) A.y += rowbase[(P) + 1 - off];                      \
        }                                                                     \
    }

__global__ __launch_bounds__(BLK) void gather_sum_max(
    const float* __restrict__ events, const int* __restrict__ indices,
    float* __restrict__ out, float* __restrict__ pmax)
{
    const int b  = blockIdx.y;
    const int cx = blockIdx.x;
    const int t  = (int)threadIdx.x;

    // wave w = t>>6 handles stripe g=w (pA) and g=w+4 (pB):
    // p = g*4096 + cx*256 + lane*4  -> one contiguous 1KB line per wave.
    const int pA = ((t >> 6) << 12) + (cx << 8) + ((t & 63) << 2);
    const int pB = pA + 16384;

    float4 accA = {0.f, 0.f, 0.f, 0.f};
    float4 accB = {0.f, 0.f, 0.f, 0.f};

    const float* evb  = events + (size_t)b * (E_ * S_);
    const int*   idxb = indices + b * E_;

#pragma unroll 4
    for (int e = 0; e < E_; ++e) {
        const int off = idxb[e];                  // block-uniform scalar load
        const float* rowbase = evb + e * S_;      // events[b,e,0]
        GATHER(accA, pA)
        GATHER(accB, pB)
    }

    // aligned float4 stores of the raw sums (same stripe pattern)
    float* ob = out + (size_t)b * S_;
    *reinterpret_cast<float4*>(ob + pA) = accA;
    *reinterpret_cast<float4*>(ob + pB) = accB;

    // thread-local max of the 8 values
    float m = fmaxf(fmaxf(fmaxf(accA.x, accA.y), fmaxf(accA.z, accA.w)),
                    fmaxf(fmaxf(accB.x, accB.y), fmaxf(accB.z, accB.w)));

    // 64-lane butterfly reduce
#pragma unroll
    for (int d = 1; d < 64; d <<= 1)
        m = fmaxf(m, __shfl_xor(m, d, 64));

    __shared__ float wmax[BLK / 64];
    if ((t & 63) == 0) wmax[t >> 6] = m;
    __syncthreads();
    if (t == 0) {
        float mm = fmaxf(fmaxf(wmax[0], wmax[1]), fmaxf(wmax[2], wmax[3]));
        pmax[b * NCH + cx] = mm;   // unique slot: no memset, no atomics
    }
}

__global__ __launch_bounds__(256) void normalize_k(
    float* __restrict__ out, const float* __restrict__ pmax)
{
    const int b = blockIdx.y;
    // redundant per-block reduce of the 16 partial maxes (L2/L3-hot)
    const float* pm = pmax + b * NCH;
    float m = pm[0];
#pragma unroll
    for (int c = 1; c < NCH; ++c) m = fmaxf(m, pm[c]);
    const float inv = 1.0f / (m + 1e-8f);

    const int i = blockIdx.x * blockDim.x + threadIdx.x;   // float4 idx in row
    float4* o4 = reinterpret_cast<float4*>(out + (size_t)b * S_);
    float4 v = o4[i];
    v.x *= inv; v.y *= inv; v.z *= inv; v.w *= inv;
    o4[i] = v;
}

extern "C" void kernel_launch(void* const* d_in, const int* in_sizes, int n_in,
                              void* d_out, int out_size, void* d_ws, size_t ws_size,
                              hipStream_t stream) {
    const float* events  = (const float*)d_in[0];
    const int*   indices = (const int*)d_in[1];
    float* out  = (float*)d_out;
    float* pmax = (float*)d_ws;          // B_*NCH floats = 8 KB, fully rewritten
                                         // by kernel A every call

    dim3 gridA(NCH, B_);                 // 16 x 128 = 2048 blocks
    gather_sum_max<<<gridA, BLK, 0, stream>>>(events, indices, out, pmax);

    dim3 gridB(S_ / 4 / 256, B_);        // 32 x 128 = 4096 blocks
    normalize_k<<<gridB, 256, 0, stream>>>(out, pmax);
}